// Round 2
// 283.158 us; speedup vs baseline: 1.1199x; 1.1199x over previous
//
#include <hip/hip_runtime.h>
#include <math.h>

// SegmentedTensorSquareSelfInteraction on MI355X (gfx950) — fully fused version.
// N=32768, MUL0=256, MUL1=128, G=64, INV_DIM=448, used gates=576, out=(N,640) fp32
//
// Two dispatches:
//  1. wcast : W1/W2[:, :576]/Wl0/Wl1 -> bf16 transposed (no padding; all N mult of 16)
//  2. fused : per block of BM=64 nodes, entire chain with zero HBM intermediates:
//     A: s_all -> LDS sa[64][472]              (pad 472: 944B stride, 16B aligned, 2-way banks)
//     B: h = silu(sa @ W1 * s1) -> LDS hb      (Bs-staged GEMM, 7 N-tiles/wave)
//     C: gates = hb @ W2 * s1 (2 passes 320+256 cols); u = sa*g0 -> hb; g1 -> LDS
//        wmat[(r*3+i)][m] = v*g1 -> overlays sa ([192][136], 272B stride)
//     D: o0 = u @ Wl0 * s1 -> LayerNorm (cross-wave LDS reduce) -> out[:, :256]
//     E: o1 = wmat @ Wl1 * s2 -> RMS over (3,128) -> out[:, 256:640]
// LDS: sa 60,416 + hb 60,416 + BsG1 35,840 + red 3,328 = 160,000 B -> 1 block/CU, 8 waves.
// ws usage: 1,179,648 bytes (transposed bf16 weights only).
//
// R1 bugfix: wmat build loop bound was 3072 (half the 64x96 float4 units) -> rows
// 96..191 of wmat were stale sa bytes incl. uninit padding cols -> Inf/NaN. Now 6144.

typedef float floatx4 __attribute__((ext_vector_type(4)));
typedef __bf16 bf16x8 __attribute__((ext_vector_type(8)));

__device__ __forceinline__ unsigned short f2bf(float f) {
    union { float f; unsigned u; } v; v.f = f;
    unsigned r = v.u + 0x7FFFu + ((v.u >> 16) & 1u);  // round-to-nearest-even
    return (unsigned short)(r >> 16);
}
__device__ __forceinline__ float bf2f(unsigned short u) {
    union { unsigned u; float f; } v; v.u = ((unsigned)u) << 16; return v.f;
}

// ---------------------------------------------------------------- weight cast
__global__ __launch_bounds__(256) void wcast_kernel(
    const float* __restrict__ W1, const float* __restrict__ W2,
    const float* __restrict__ Wl0, const float* __restrict__ Wl1,
    unsigned short* __restrict__ W1T, unsigned short* __restrict__ W2T,
    unsigned short* __restrict__ Wl0T, unsigned short* __restrict__ Wl1T)
{
    int idx = blockIdx.x * 256 + threadIdx.x;
    if (idx < 200704) {                           // W1T: 448 x 448, W1T[j][k]=W1[k][j]
        int j = idx / 448, k = idx - j * 448;
        W1T[idx] = f2bf(W1[k * 448 + j]);
    } else if (idx < 200704 + 258048) {           // W2T: 576 x 448 (first 576 cols of W2)
        int r = idx - 200704;
        int j = r / 448, k = r - j * 448;
        W2T[r] = f2bf(W2[k * 832 + j]);
    } else if (idx < 200704 + 258048 + 114688) {  // Wl0T: 256 x 448
        int r = idx - (200704 + 258048);
        int j = r / 448, k = r - j * 448;
        Wl0T[r] = f2bf(Wl0[k * 256 + j]);
    } else if (idx < 200704 + 258048 + 114688 + 16384) {  // Wl1T: 128 x 128
        int r = idx - (200704 + 258048 + 114688);
        int j = r / 128, m = r - j * 128;
        Wl1T[r] = f2bf(Wl1[m * 128 + j]);
    }
}

// ---------------------------------------------------------------- GEMM k-step engine
// acc[MT][NT] += A_lds @ Bs, staging Bt k-chunks into Bs[cols][40] per k-step.
// Wave layout: per wave MT M-tiles at rowBase + mt*16, NT N-tiles at (wn + 4*j)*16.
template<int MT, int NT>
__device__ __forceinline__ void gemm_ktiles(
    const unsigned short* __restrict__ Bt, const int ldb, const int kTot, const int colBase,
    const unsigned short* __restrict__ Albs, const int ldsA, const int rowBase,
    unsigned short* __restrict__ Bs,
    const int tid, const int l15, const int quad, const int wn,
    floatx4 (&acc)[MT][NT])
{
    constexpr int NU = NT * 256;   // uint4 chunks per k-step: NT*64 cols * 4 parts
    for (int k0 = 0; k0 < kTot; k0 += 32) {
        __syncthreads();           // protect Bs from previous iteration's readers
        #pragma unroll
        for (int u0 = 0; u0 < NU; u0 += 512) {
            int u = u0 + tid;
            if (u0 + 512 <= NU || u < NU) {
                int col = u >> 2, part = u & 3;
                *(uint4*)&Bs[col * 40 + part * 8] =
                    *(const uint4*)(Bt + (colBase + col) * ldb + k0 + part * 8);
            }
        }
        __syncthreads();
        bf16x8 af[MT];
        #pragma unroll
        for (int mt = 0; mt < MT; ++mt)
            af[mt] = *(const bf16x8*)&Albs[(rowBase + mt * 16 + l15) * ldsA + k0 + quad * 8];
        #pragma unroll
        for (int j = 0; j < NT; ++j) {
            bf16x8 bfv = *(const bf16x8*)&Bs[((wn + 4 * j) * 16 + l15) * 40 + quad * 8];
            #pragma unroll
            for (int mt = 0; mt < MT; ++mt)
                acc[mt][j] = __builtin_amdgcn_mfma_f32_16x16x32_bf16(af[mt], bfv, acc[mt][j], 0, 0, 0);
        }
    }
}

// ---------------------------------------------------------------- fused megakernel
__global__ __launch_bounds__(512, 2) void fused_kernel(
    const float* __restrict__ x,
    const unsigned short* __restrict__ W1T,
    const unsigned short* __restrict__ W2T,
    const unsigned short* __restrict__ Wl0T,
    const unsigned short* __restrict__ Wl1T,
    float* __restrict__ out)
{
    __shared__ unsigned short sa[64][472];   // s_all; later wmat overlay [192][136]
    __shared__ unsigned short hb[64][472];   // h, then u
    __shared__ unsigned short BsG1[17920];   // B staging [<=448][40]; later g1 [64][128]
    __shared__ float red[832];               // LN partials [64][8]; rowSq [192][4]; nodeRms @768

    const int tid  = threadIdx.x;
    const int lane = tid & 63;
    const int l15  = lane & 15;
    const int quad = lane >> 4;
    const int w    = tid >> 6;
    const int wm   = w >> 2;        // 0..1 : rows wm*32 .. wm*32+31
    const int wn   = w & 3;         // 0..3 : N-tile = wn + 4*j
    const int n0   = blockIdx.x * 64;

    const float s1 = 0.047245559f;  // 1/sqrt(448)
    const float s2 = 0.088388348f;  // 1/sqrt(128)

    // ---- stage A: s_all -> sa ----
    {
        const int r = tid >> 3, sub = tid & 7;     // 8 threads per row
        const float* xr = x + (size_t)(n0 + r) * 640;
        #pragma unroll
        for (int i = 0; i < 8; ++i) {              // s part: 64 float4 per row
            int c4 = i * 8 + sub;
            float4 f = *(const float4*)(xr + c4 * 4);
            uint2 p;
            p.x = (unsigned)f2bf(f.x) | ((unsigned)f2bf(f.y) << 16);
            p.y = (unsigned)f2bf(f.z) | ((unsigned)f2bf(f.w) << 16);
            *(uint2*)&sa[r][c4 * 4] = p;
        }
        const float* xv = xr + 256;
        #pragma unroll
        for (int i = 0; i < 8; ++i) {              // t0 part: 64 groups per row
            int g = i * 8 + sub;
            const float2* vg = (const float2*)(xv + 6 * g);
            float2 p0 = vg[0], p1 = vg[1], p2 = vg[2];
            float ax = p0.x, ay = p0.y, az = p1.x;
            float bx = p1.y, by = p2.x, bz = p2.y;
            float aa = ax*ax + ay*ay + az*az;
            float ab = ax*bx + ay*by + az*bz;
            float bb = bx*bx + by*by + bz*bz;
            const float ISQ3 = 0.57735026918962576f;
            const float SQ2  = 1.41421356237309505f;
            sa[r][256 + 3*g]     = f2bf(aa * ISQ3);
            sa[r][256 + 3*g + 1] = f2bf(SQ2 * ab * ISQ3);
            sa[r][256 + 3*g + 2] = f2bf(bb * ISQ3);
        }
    }
    // visibility handled by gemm's double barrier

    // ---- stage B: h = silu(sa @ W1 * s1) -> hb ----
    {
        floatx4 acc[2][7] = {};
        gemm_ktiles<2,7>(W1T, 448, 448, 0, &sa[0][0], 472, wm*32, BsG1, tid, l15, quad, wn, acc);
        #pragma unroll
        for (int j = 0; j < 7; ++j) {
            const int col = (wn + 4*j) * 16 + l15;
            #pragma unroll
            for (int mt = 0; mt < 2; ++mt)
                #pragma unroll
                for (int r = 0; r < 4; ++r) {
                    float v = acc[mt][j][r] * s1;
                    v = v / (1.f + __expf(-v));
                    hb[wm*32 + mt*16 + quad*4 + r][col] = f2bf(v);
                }
        }
    }

    // ---- stage C: gates = hb @ W2 * s1; u -> hb; g1 -> BsG1 ----
    {
        floatx4 acc1[2][5] = {};
        floatx4 acc2[2][4] = {};
        gemm_ktiles<2,5>(W2T, 448, 448, 0,   &hb[0][0], 472, wm*32, BsG1, tid, l15, quad, wn, acc1);
        gemm_ktiles<2,4>(W2T, 448, 448, 320, &hb[0][0], 472, wm*32, BsG1, tid, l15, quad, wn, acc2);
        __syncthreads();   // all hb(h) reads + Bs reads complete
        unsigned short* g1p = BsG1;
        #pragma unroll
        for (int j = 0; j < 5; ++j) {                 // pass-1 cols 0..319: all g0 -> u
            const int col = (wn + 4*j) * 16 + l15;
            #pragma unroll
            for (int mt = 0; mt < 2; ++mt)
                #pragma unroll
                for (int r = 0; r < 4; ++r) {
                    const int row = wm*32 + mt*16 + quad*4 + r;
                    hb[row][col] = f2bf(bf2f(sa[row][col]) * (acc1[mt][j][r] * s1));
                }
        }
        #pragma unroll
        for (int j = 0; j < 4; ++j) {                 // pass-2 cols 320..575: g0 | g1o
            const int colb = 320 + (wn + 4*j) * 16;   // wave-uniform
            if (colb < 448) {
                const int col = colb + l15;
                #pragma unroll
                for (int mt = 0; mt < 2; ++mt)
                    #pragma unroll
                    for (int r = 0; r < 4; ++r) {
                        const int row = wm*32 + mt*16 + quad*4 + r;
                        hb[row][col] = f2bf(bf2f(sa[row][col]) * (acc2[mt][j][r] * s1));
                    }
            } else {
                const int m = colb - 448 + l15;
                #pragma unroll
                for (int mt = 0; mt < 2; ++mt)
                    #pragma unroll
                    for (int r = 0; r < 4; ++r) {
                        const int row = wm*32 + mt*16 + quad*4 + r;
                        g1p[row * 128 + m] = f2bf(acc2[mt][j][r] * s1);
                    }
            }
        }
        __syncthreads();   // u/g1 ready; sa dead
    }

    // ---- wmat build: wmat[(r*3+i)][m] = v[r][m][i] * g1[r][m] -> overlays sa ----
    {
        unsigned short* wmp = &sa[0][0];          // [192][136]
        const unsigned short* g1p = BsG1;
        #pragma unroll
        for (int e0 = 0; e0 < 6144; e0 += 512) {  // 64 rows * 96 float4
            int e4 = e0 + tid;
            int rl = e4 / 96;
            int c4 = (e4 - rl * 96) * 4;          // float index in v-row (0..383)
            float4 xv = *(const float4*)(x + (size_t)(n0 + rl) * 640 + 256 + c4);
            float vv[4] = {xv.x, xv.y, xv.z, xv.w};
            #pragma unroll
            for (int d = 0; d < 4; ++d) {
                int rem = c4 + d;
                int m = rem / 3;
                int i = rem - 3 * m;
                wmp[(rl * 3 + i) * 136 + m] = f2bf(vv[d] * bf2f(g1p[rl * 128 + m]));
            }
        }
        __syncthreads();
    }

    // ---- stage D: o0 = u @ Wl0 * s1 -> LayerNorm -> out[:, :256] ----
    {
        floatx4 acc[2][4] = {};
        gemm_ktiles<2,4>(Wl0T, 448, 448, 0, &hb[0][0], 472, wm*32, BsG1, tid, l15, quad, wn, acc);
        #pragma unroll
        for (int mt = 0; mt < 2; ++mt)
            #pragma unroll
            for (int r = 0; r < 4; ++r) {
                float sv = 0.f, sq = 0.f;
                #pragma unroll
                for (int j = 0; j < 4; ++j) {
                    float v = acc[mt][j][r] * s1;
                    sv += v; sq += v * v;
                }
                #pragma unroll
                for (int off = 1; off <= 8; off <<= 1) {
                    sv += __shfl_xor(sv, off);
                    sq += __shfl_xor(sq, off);
                }
                if (l15 == 0) {
                    const int row = wm*32 + mt*16 + quad*4 + r;
                    red[row * 8 + wn * 2]     = sv;
                    red[row * 8 + wn * 2 + 1] = sq;
                }
            }
        __syncthreads();
        #pragma unroll
        for (int mt = 0; mt < 2; ++mt)
            #pragma unroll
            for (int r = 0; r < 4; ++r) {
                const int row = wm*32 + mt*16 + quad*4 + r;
                float ts = red[row*8+0] + red[row*8+2] + red[row*8+4] + red[row*8+6];
                float tq = red[row*8+1] + red[row*8+3] + red[row*8+5] + red[row*8+7];
                float mu  = ts * (1.f/256.f);
                float var = tq * (1.f/256.f) - mu * mu;
                float rln = rsqrtf(var + 1e-6f);
                float* orow = out + (size_t)(n0 + row) * 640;
                #pragma unroll
                for (int j = 0; j < 4; ++j)
                    orow[(wn + 4*j)*16 + l15] = (acc[mt][j][r] * s1 - mu) * rln;
            }
    }

    // ---- stage E: o1 = wmat @ Wl1 * s2 -> RMS over (3,128) -> out[:, 256:640] ----
    {
        floatx4 acc[6][2] = {};
        gemm_ktiles<6,2>(Wl1T, 128, 128, 0, &sa[0][0] /*wmat*/, 136, wm*96, BsG1, tid, l15, quad, wn, acc);
        #pragma unroll
        for (int mt = 0; mt < 6; ++mt)
            #pragma unroll
            for (int r = 0; r < 4; ++r) {
                float q = 0.f;
                #pragma unroll
                for (int j = 0; j < 2; ++j) {
                    float v = acc[mt][j][r] * s2;
                    q += v * v;
                }
                #pragma unroll
                for (int off = 1; off <= 8; off <<= 1) q += __shfl_xor(q, off);
                if (l15 == 0) {
                    const int row = wm*96 + mt*16 + quad*4 + r;
                    red[row * 4 + wn] = q;    // safe: all waves past stage-D red reads
                }
            }
        __syncthreads();
        if (tid < 64) {                        // per-node rrms
            float s = 0.f;
            #pragma unroll
            for (int rr = 0; rr < 3; ++rr)
                #pragma unroll
                for (int w2 = 0; w2 < 4; ++w2)
                    s += red[(tid*3 + rr) * 4 + w2];
            red[768 + tid] = rsqrtf(s * (1.f/384.f) + 1e-6f);
        }
        __syncthreads();
        #pragma unroll
        for (int mt = 0; mt < 6; ++mt)
            #pragma unroll
            for (int r = 0; r < 4; ++r) {
                const int row = wm*96 + mt*16 + quad*4 + r;
                const int nl  = row / 3;
                const int i   = row - 3 * nl;
                const float rms = red[768 + nl];
                float* op = out + (size_t)(n0 + nl) * 640 + 256 + i;
                #pragma unroll
                for (int j = 0; j < 2; ++j)
                    op[3 * ((wn + 4*j)*16 + l15)] = acc[mt][j][r] * s2 * rms;
            }
    }
}

// ---------------------------------------------------------------- launch
extern "C" void kernel_launch(void* const* d_in, const int* in_sizes, int n_in,
                              void* d_out, int out_size, void* d_ws, size_t ws_size,
                              hipStream_t stream) {
    const float* x   = (const float*)d_in[0];
    const float* W1  = (const float*)d_in[1];
    const float* W2  = (const float*)d_in[2];
    const float* Wl0 = (const float*)d_in[3];
    const float* Wl1 = (const float*)d_in[4];
    float* out = (float*)d_out;
    char* ws = (char*)d_ws;

    unsigned short* W1T  = (unsigned short*)(ws + 0);         // 401,408 B
    unsigned short* W2T  = (unsigned short*)(ws + 401408);    // 516,096 B
    unsigned short* Wl0T = (unsigned short*)(ws + 917504);    // 229,376 B
    unsigned short* Wl1T = (unsigned short*)(ws + 1146880);   //  32,768 B
    // peak ws: 1,179,648 bytes

    wcast_kernel<<<dim3(2304), dim3(256), 0, stream>>>(W1, W2, Wl0, Wl1, W1T, W2T, Wl0T, Wl1T);
    fused_kernel<<<dim3(512), dim3(512), 0, stream>>>(x, W1T, W2T, Wl0T, Wl1T, out);
}

// Round 3
// 259.368 us; speedup vs baseline: 1.2226x; 1.0917x over previous
//
#include <hip/hip_runtime.h>
#include <math.h>

// SegmentedTensorSquareSelfInteraction on MI355X (gfx950) — fused, streaming-B version.
// N=32768, MUL0=256, MUL1=128, G=64, INV_DIM=448, used gates=576, out=(N,640) fp32
//
// Two dispatches:
//  1. wcast : weights -> bf16 in MFMA *fragment order*:
//             BF[tile][kc][lane][8] = B[k = kc*32+(lane>>4)*8+e][col = tile*16+(lane&15)]
//             so a wave's B-fragment load is one coalesced 1KB global_load_dwordx4 (L2-resident).
//  2. fused : per block of 64 nodes, whole chain with zero HBM intermediates and
//             *barrier-free* GEMM k-loops (no B staging in LDS):
//     A: s_all -> LDS sa[64][472]
//     B: h = silu(sa @ W1 * s1) -> LDS hb      (stream W1F, NT=7)
//     C: gates = hb @ W2 * s1 (single NT=9 pass); u = sa*g0 -> hb; g1 -> LDS g1[64][128]
//        wmat[(r*3+i)][m] = v*g1 -> overlays sa ([192][136])
//     D: o0 = u @ Wl0 * s1 -> LayerNorm -> out[:, :256]
//     E: o1 = wmat @ Wl1 * s2 -> RMS over (3,128) -> out[:, 256:640]
// LDS: sa 60,416 + hb 60,416 + g1 16,384 + red 3,328 = 140,544 B -> 1 block/CU, 8 waves.
// ws usage: 1,179,648 bytes (fragment-ordered bf16 weights only).

typedef float floatx4 __attribute__((ext_vector_type(4)));
typedef __bf16 bf16x8 __attribute__((ext_vector_type(8)));

__device__ __forceinline__ unsigned short f2bf(float f) {
    union { float f; unsigned u; } v; v.f = f;
    unsigned r = v.u + 0x7FFFu + ((v.u >> 16) & 1u);  // round-to-nearest-even
    return (unsigned short)(r >> 16);
}
__device__ __forceinline__ float bf2f(unsigned short u) {
    union { unsigned u; float f; } v; v.u = ((unsigned)u) << 16; return v.f;
}

// ---------------------------------------------------------------- weight cast
// Fragment order: within each matrix, dst idx = ((t*NKC + kc)*64 + lane)*8 + e
//   col = t*16 + (lane&15), k = kc*32 + (lane>>4)*8 + e, src = W[k*ldW + col].
__global__ __launch_bounds__(256) void wcast_kernel(
    const float* __restrict__ W1, const float* __restrict__ W2,
    const float* __restrict__ Wl0, const float* __restrict__ Wl1,
    unsigned short* __restrict__ W1F, unsigned short* __restrict__ W2F,
    unsigned short* __restrict__ Wl0F, unsigned short* __restrict__ Wl1F)
{
    int idx = blockIdx.x * 256 + threadIdx.x;
    if (idx < 200704) {                           // W1F: 28 tiles x 14 kc (448x448, ld 448)
        int e = idx & 7, lane = (idx >> 3) & 63, r2 = idx >> 9;
        int kc = r2 % 14, t = r2 / 14;
        int col = t * 16 + (lane & 15);
        int k   = kc * 32 + (lane >> 4) * 8 + e;
        W1F[idx] = f2bf(W1[k * 448 + col]);
    } else if (idx < 458752) {                    // W2F: 36 tiles x 14 kc (576 of 832 cols)
        int r = idx - 200704;
        int e = r & 7, lane = (r >> 3) & 63, r2 = r >> 9;
        int kc = r2 % 14, t = r2 / 14;
        int col = t * 16 + (lane & 15);
        int k   = kc * 32 + (lane >> 4) * 8 + e;
        W2F[r] = f2bf(W2[k * 832 + col]);
    } else if (idx < 573440) {                    // Wl0F: 16 tiles x 14 kc (448x256)
        int r = idx - 458752;
        int e = r & 7, lane = (r >> 3) & 63, r2 = r >> 9;
        int kc = r2 % 14, t = r2 / 14;
        int col = t * 16 + (lane & 15);
        int k   = kc * 32 + (lane >> 4) * 8 + e;
        Wl0F[r] = f2bf(Wl0[k * 256 + col]);
    } else if (idx < 589824) {                    // Wl1F: 8 tiles x 4 kc (128x128)
        int r = idx - 573440;
        int e = r & 7, lane = (r >> 3) & 63, r2 = r >> 9;
        int kc = r2 % 4, t = r2 / 4;
        int col = t * 16 + (lane & 15);
        int k   = kc * 32 + (lane >> 4) * 8 + e;
        Wl1F[r] = f2bf(Wl1[k * 128 + col]);
    }
}

// ---------------------------------------------------------------- streaming GEMM core
// acc[MT][NT] += A_lds[rows] @ B (fragment-ordered global, L2-resident). No barriers,
// no LDS staging: per kc, MT ds_read_b128 (A) + NT coalesced 16B global loads (B) + MFMAs.
template<int MT, int NT, int NKC>
__device__ __forceinline__ void gemm_stream(
    const unsigned short* __restrict__ BF, const int tileBase,
    const unsigned short* __restrict__ Albs, const int ldsA, const int rowBase,
    const int lane, const int l15, const int quad, const int wn,
    floatx4 (&acc)[MT][NT])
{
    const unsigned short* bp[NT];
    #pragma unroll
    for (int j = 0; j < NT; ++j)
        bp[j] = BF + ((size_t)(tileBase + wn + 4 * j) * NKC * 64 + lane) * 8;
    #pragma unroll
    for (int kc = 0; kc < NKC; ++kc) {
        bf16x8 af[MT];
        #pragma unroll
        for (int mt = 0; mt < MT; ++mt)
            af[mt] = *(const bf16x8*)&Albs[(rowBase + mt * 16 + l15) * ldsA + kc * 32 + quad * 8];
        #pragma unroll
        for (int j = 0; j < NT; ++j) {
            bf16x8 bfv = *(const bf16x8*)(bp[j] + kc * 512);
            #pragma unroll
            for (int mt = 0; mt < MT; ++mt)
                acc[mt][j] = __builtin_amdgcn_mfma_f32_16x16x32_bf16(af[mt], bfv, acc[mt][j], 0, 0, 0);
        }
    }
}

// ---------------------------------------------------------------- fused megakernel
__global__ __launch_bounds__(512, 2) void fused_kernel(
    const float* __restrict__ x,
    const unsigned short* __restrict__ W1F,
    const unsigned short* __restrict__ W2F,
    const unsigned short* __restrict__ Wl0F,
    const unsigned short* __restrict__ Wl1F,
    float* __restrict__ out)
{
    __shared__ unsigned short sa[64][472];   // s_all; later wmat overlay [192][136]
    __shared__ unsigned short hb[64][472];   // h, then u
    __shared__ unsigned short g1[64][128];   // g1o gates
    __shared__ float red[832];               // LN partials [64][8]; rowSq [192][4]; nodeRms @768

    const int tid  = threadIdx.x;
    const int lane = tid & 63;
    const int l15  = lane & 15;
    const int quad = lane >> 4;
    const int w    = tid >> 6;
    const int wm   = w >> 2;        // 0..1 : rows wm*32 .. wm*32+31 (wm*96 in stage E)
    const int wn   = w & 3;         // 0..3 : N-tile = wn + 4*j
    const int n0   = blockIdx.x * 64;

    const float s1 = 0.047245559f;  // 1/sqrt(448)
    const float s2 = 0.088388348f;  // 1/sqrt(128)

    // ---- stage A: s_all -> sa ----
    {
        const int r = tid >> 3, sub = tid & 7;     // 8 threads per row
        const float* xr = x + (size_t)(n0 + r) * 640;
        #pragma unroll
        for (int i = 0; i < 8; ++i) {              // s part: 64 float4 per row
            int c4 = i * 8 + sub;
            float4 f = *(const float4*)(xr + c4 * 4);
            uint2 p;
            p.x = (unsigned)f2bf(f.x) | ((unsigned)f2bf(f.y) << 16);
            p.y = (unsigned)f2bf(f.z) | ((unsigned)f2bf(f.w) << 16);
            *(uint2*)&sa[r][c4 * 4] = p;
        }
        const float* xv = xr + 256;
        #pragma unroll
        for (int i = 0; i < 8; ++i) {              // t0 part: 64 groups per row
            int g = i * 8 + sub;
            const float2* vg = (const float2*)(xv + 6 * g);
            float2 p0 = vg[0], p1 = vg[1], p2 = vg[2];
            float ax = p0.x, ay = p0.y, az = p1.x;
            float bx = p1.y, by = p2.x, bz = p2.y;
            float aa = ax*ax + ay*ay + az*az;
            float ab = ax*bx + ay*by + az*bz;
            float bb = bx*bx + by*by + bz*bz;
            const float ISQ3 = 0.57735026918962576f;
            const float SQ2  = 1.41421356237309505f;
            sa[r][256 + 3*g]     = f2bf(aa * ISQ3);
            sa[r][256 + 3*g + 1] = f2bf(SQ2 * ab * ISQ3);
            sa[r][256 + 3*g + 2] = f2bf(bb * ISQ3);
        }
    }
    __syncthreads();                               // sa ready

    // ---- stage B: h = silu(sa @ W1 * s1) -> hb ----
    {
        floatx4 acc[2][7] = {};
        gemm_stream<2,7,14>(W1F, 0, &sa[0][0], 472, wm*32, lane, l15, quad, wn, acc);
        #pragma unroll
        for (int j = 0; j < 7; ++j) {
            const int col = (wn + 4*j) * 16 + l15;
            #pragma unroll
            for (int mt = 0; mt < 2; ++mt)
                #pragma unroll
                for (int r = 0; r < 4; ++r) {
                    float v = acc[mt][j][r] * s1;
                    v = v / (1.f + __expf(-v));
                    hb[wm*32 + mt*16 + quad*4 + r][col] = f2bf(v);
                }
        }
    }
    __syncthreads();                               // hb(h) ready

    // ---- stage C: gates = hb @ W2 * s1 (single NT=9 pass); u -> hb; g1 -> g1[][] ----
    {
        floatx4 acc[2][9] = {};
        gemm_stream<2,9,14>(W2F, 0, &hb[0][0], 472, wm*32, lane, l15, quad, wn, acc);
        __syncthreads();                           // all hb(h) reads complete
        #pragma unroll
        for (int j = 0; j < 9; ++j) {
            const int colb = (wn + 4*j) * 16;      // wave-uniform, 0..560
            if (colb < 448) {                      // g0 -> u = sa * g0
                const int col = colb + l15;
                #pragma unroll
                for (int mt = 0; mt < 2; ++mt)
                    #pragma unroll
                    for (int r = 0; r < 4; ++r) {
                        const int row = wm*32 + mt*16 + quad*4 + r;
                        hb[row][col] = f2bf(bf2f(sa[row][col]) * (acc[mt][j][r] * s1));
                    }
            } else {                               // g1o
                const int m = colb - 448 + l15;
                #pragma unroll
                for (int mt = 0; mt < 2; ++mt)
                    #pragma unroll
                    for (int r = 0; r < 4; ++r) {
                        const int row = wm*32 + mt*16 + quad*4 + r;
                        g1[row][m] = f2bf(acc[mt][j][r] * s1);
                    }
            }
        }
    }
    __syncthreads();                               // u/g1 ready; sa dead

    // ---- wmat build: wmat[(r*3+i)][m] = v[r][m][i] * g1[r][m] -> overlays sa ----
    {
        unsigned short* wmp = &sa[0][0];           // [192][136]
        #pragma unroll
        for (int e0 = 0; e0 < 6144; e0 += 512) {   // 64 rows * 96 float4
            int e4 = e0 + tid;
            int rl = e4 / 96;
            int c4 = (e4 - rl * 96) * 4;           // float index in v-row (0..383)
            float4 xv = *(const float4*)(x + (size_t)(n0 + rl) * 640 + 256 + c4);
            float vv[4] = {xv.x, xv.y, xv.z, xv.w};
            #pragma unroll
            for (int d = 0; d < 4; ++d) {
                int rem = c4 + d;
                int m = rem / 3;
                int i = rem - 3 * m;
                wmp[(rl * 3 + i) * 136 + m] = f2bf(vv[d] * bf2f(g1[rl][m]));
            }
        }
    }
    __syncthreads();                               // wmat ready

    // ---- stage D: o0 = u @ Wl0 * s1 -> LayerNorm -> out[:, :256] ----
    {
        floatx4 acc[2][4] = {};
        gemm_stream<2,4,14>(Wl0F, 0, &hb[0][0], 472, wm*32, lane, l15, quad, wn, acc);
        #pragma unroll
        for (int mt = 0; mt < 2; ++mt)
            #pragma unroll
            for (int r = 0; r < 4; ++r) {
                float sv = 0.f, sq = 0.f;
                #pragma unroll
                for (int j = 0; j < 4; ++j) {
                    float v = acc[mt][j][r] * s1;
                    sv += v; sq += v * v;
                }
                #pragma unroll
                for (int off = 1; off <= 8; off <<= 1) {
                    sv += __shfl_xor(sv, off);
                    sq += __shfl_xor(sq, off);
                }
                if (l15 == 0) {
                    const int row = wm*32 + mt*16 + quad*4 + r;
                    red[row * 8 + wn * 2]     = sv;
                    red[row * 8 + wn * 2 + 1] = sq;
                }
            }
        __syncthreads();                           // LN partials ready
        #pragma unroll
        for (int mt = 0; mt < 2; ++mt)
            #pragma unroll
            for (int r = 0; r < 4; ++r) {
                const int row = wm*32 + mt*16 + quad*4 + r;
                float ts = red[row*8+0] + red[row*8+2] + red[row*8+4] + red[row*8+6];
                float tq = red[row*8+1] + red[row*8+3] + red[row*8+5] + red[row*8+7];
                float mu  = ts * (1.f/256.f);
                float var = tq * (1.f/256.f) - mu * mu;
                float rln = rsqrtf(var + 1e-6f);
                float* orow = out + (size_t)(n0 + row) * 640;
                #pragma unroll
                for (int j = 0; j < 4; ++j)
                    orow[(wn + 4*j)*16 + l15] = (acc[mt][j][r] * s1 - mu) * rln;
            }
    }
    __syncthreads();                               // stage-D red reads done before E writes red

    // ---- stage E: o1 = wmat @ Wl1 * s2 -> RMS over (3,128) -> out[:, 256:640] ----
    {
        floatx4 acc[6][2] = {};
        gemm_stream<6,2,4>(Wl1F, 0, &sa[0][0] /*wmat*/, 136, wm*96, lane, l15, quad, wn, acc);
        #pragma unroll
        for (int mt = 0; mt < 6; ++mt)
            #pragma unroll
            for (int r = 0; r < 4; ++r) {
                float q = 0.f;
                #pragma unroll
                for (int j = 0; j < 2; ++j) {
                    float v = acc[mt][j][r] * s2;
                    q += v * v;
                }
                #pragma unroll
                for (int off = 1; off <= 8; off <<= 1) q += __shfl_xor(q, off);
                if (l15 == 0) {
                    const int row = wm*96 + mt*16 + quad*4 + r;
                    red[row * 4 + wn] = q;
                }
            }
        __syncthreads();
        if (tid < 64) {                            // per-node rrms
            float s = 0.f;
            #pragma unroll
            for (int rr = 0; rr < 3; ++rr)
                #pragma unroll
                for (int w2 = 0; w2 < 4; ++w2)
                    s += red[(tid*3 + rr) * 4 + w2];
            red[768 + tid] = rsqrtf(s * (1.f/384.f) + 1e-6f);
        }
        __syncthreads();
        #pragma unroll
        for (int mt = 0; mt < 6; ++mt)
            #pragma unroll
            for (int r = 0; r < 4; ++r) {
                const int row = wm*96 + mt*16 + quad*4 + r;
                const int nl  = row / 3;
                const int i   = row - 3 * nl;
                const float rms = red[768 + nl];
                float* op = out + (size_t)(n0 + nl) * 640 + 256 + i;
                #pragma unroll
                for (int j = 0; j < 2; ++j)
                    op[3 * ((wn + 4*j)*16 + l15)] = acc[mt][j][r] * s2 * rms;
            }
    }
}

// ---------------------------------------------------------------- launch
extern "C" void kernel_launch(void* const* d_in, const int* in_sizes, int n_in,
                              void* d_out, int out_size, void* d_ws, size_t ws_size,
                              hipStream_t stream) {
    const float* x   = (const float*)d_in[0];
    const float* W1  = (const float*)d_in[1];
    const float* W2  = (const float*)d_in[2];
    const float* Wl0 = (const float*)d_in[3];
    const float* Wl1 = (const float*)d_in[4];
    float* out = (float*)d_out;
    char* ws = (char*)d_ws;

    unsigned short* W1F  = (unsigned short*)(ws + 0);         // 401,408 B
    unsigned short* W2F  = (unsigned short*)(ws + 401408);    // 516,096 B
    unsigned short* Wl0F = (unsigned short*)(ws + 917504);    // 229,376 B
    unsigned short* Wl1F = (unsigned short*)(ws + 1146880);   //  32,768 B
    // peak ws: 1,179,648 bytes

    wcast_kernel<<<dim3(2304), dim3(256), 0, stream>>>(W1, W2, Wl0, Wl1, W1F, W2F, Wl0F, Wl1F);
    fused_kernel<<<dim3(512), dim3(512), 0, stream>>>(x, W1F, W2F, Wl0F, Wl1F, out);
}